// Round 3
// baseline (56.122 us; speedup 1.0000x reference)
//
#include <hip/hip_runtime.h>

#define HEIGHT 8

// 6 contiguous floats = two adjacent pixels (x, x+1) of one row, all 3 channels.
struct __attribute__((aligned(4))) Seg6 { float p[6]; };

// One block per box, 4*mw threads (256 for mw=64). Each thread: one column j,
// two rows (i0, i0+1). Texel gathers are 2x24B contiguous segment loads per
// sample instead of 12 scalar dwords. Output staged in LDS, stored as float4.
__global__ void __launch_bounds__(256)
roi_rotate_kernel(const float* __restrict__ images,
                  const float* __restrict__ boxes,
                  const int* __restrict__ box_indices,
                  float* __restrict__ crops,
                  float* __restrict__ width_out,
                  int max_width, int Himg, int Wimg)
{
    const int m   = blockIdx.x;
    const int tid = threadIdx.x;
    const int mw  = max_width;
    const int tpc = HEIGHT / 2;          // threads per column = 4
    const int j   = tid / tpc;           // each wave covers 16 consecutive cols
    const int i0  = (tid - j * tpc) * 2; // rows i0 and i0+1

    // Block-uniform box params -> scalar loads.
    const float x1  = boxes[m * 5 + 0];
    const float y1  = boxes[m * 5 + 1];
    const float x2  = boxes[m * 5 + 2];
    const float y2  = boxes[m * 5 + 3];
    const float ang = boxes[m * 5 + 4];
    const float bwd = x2 - x1, bhd = y2 - y1;
    const float width = (float)HEIGHT * bwd / bhd;
    const float cx = (x1 + x2) * 0.5f;
    const float cy = (y1 + y2) * 0.5f;
    const float s  = bhd / (float)HEIGHT;
    const float ca = cosf(ang);
    const float sa = sinf(ang);
    if (tid == 0) width_out[m] = (float)mw - width;

    const int b = box_indices[m];
    const float* img = images + (size_t)b * Himg * Wimg * 3;

    const float dx   = s * ((float)j - (width - 1.0f) * 0.5f);
    const float wlim = ceilf(width);
    const bool  jok  = ((float)j < wlim);

    float v[2][3] = {{0.f, 0.f, 0.f}, {0.f, 0.f, 0.f}};

    #pragma unroll
    for (int t = 0; t < 2; ++t) {
        const int   i  = i0 + t;
        const float dy = s * ((float)i - ((float)HEIGHT - 1.0f) * 0.5f);
        const float sx = cx + ca * dx - sa * dy;
        const float sy = cy + sa * dx + ca * dy;
        const bool valid = jok &&
                           (sx >= 0.0f) && (sx <= (float)(Wimg - 1)) &&
                           (sy >= 0.0f) && (sy <= (float)(Himg - 1));
        if (!valid) continue;

        const float x0 = floorf(sx);
        const float y0 = floorf(sy);
        const float fx = sx - x0;
        const float fy = sy - y0;
        // Within valid: x0i in [0,511], x1i = min(x0i+1, W-1); same for y.
        const int x0i = (int)x0;
        const int y0i = (int)y0;
        const int y1i = min(y0i + 1, Himg - 1);
        const int xb  = min(x0i, Wimg - 2);          // segment base column
        const int off0 = (x0i - xb) * 3;             // 0, or 3 at right border
        const int off1 = (min(x0i + 1, Wimg - 1) - xb) * 3;

        const float* r0 = img + ((size_t)y0i * Wimg + xb) * 3;
        const float* r1 = img + ((size_t)y1i * Wimg + xb) * 3;
        const Seg6 s0 = *(const Seg6*)r0;            // 24B: both x-pixels, row y0
        const Seg6 s1 = *(const Seg6*)r1;            // 24B: both x-pixels, row y1

        const float w00 = (1.0f - fx) * (1.0f - fy);
        const float w01 = fx * (1.0f - fy);
        const float w10 = (1.0f - fx) * fy;
        const float w11 = fx * fy;

        #pragma unroll
        for (int c = 0; c < 3; ++c) {
            v[t][c] = s0.p[off0 + c] * w00 + s0.p[off1 + c] * w01 +
                      s1.p[off0 + c] * w10 + s1.p[off1 + c] * w11;
        }
    }

    // Stage in LDS in output order, then coalesced float4 stores.
    __shared__ float lds[HEIGHT * (3 * 64 + 4)];
    float* oblk = crops + (size_t)m * HEIGHT * mw * 3;

    if (mw <= 64 && (mw & 3) == 0) {
        const int STRIDE = 3 * mw + 4;
        #pragma unroll
        for (int t = 0; t < 2; ++t) {
            float* dst = &lds[(i0 + t) * STRIDE + j * 3];
            dst[0] = v[t][0]; dst[1] = v[t][1]; dst[2] = v[t][2];
        }
        __syncthreads();
        const int nf4 = (HEIGHT * mw * 3) >> 2;      // 384 for mw=64
        for (int t4 = tid; t4 < nf4; t4 += blockDim.x) {
            const int f   = t4 * 4;
            const int ii  = f / (3 * mw);
            const int rem = f - ii * (3 * mw);
            const float4 val = *(const float4*)&lds[ii * STRIDE + rem];
            *(float4*)&oblk[f] = val;
        }
    } else {
        #pragma unroll
        for (int t = 0; t < 2; ++t) {
            float* o = oblk + ((size_t)(i0 + t) * mw + j) * 3;
            o[0] = v[t][0]; o[1] = v[t][1]; o[2] = v[t][2];
        }
    }
}

extern "C" void kernel_launch(void* const* d_in, const int* in_sizes, int n_in,
                              void* d_out, int out_size, void* d_ws, size_t ws_size,
                              hipStream_t stream) {
    const float* images      = (const float*)d_in[0];
    const float* boxes       = (const float*)d_in[2];
    const int*   box_indices = (const int*)d_in[3];

    const int M  = in_sizes[3];                       // 8192 boxes
    const int mw = (out_size - M) / (M * HEIGHT * 3); // max_width (=64)
    const int Himg = 512, Wimg = 512;

    float* crops     = (float*)d_out;
    float* width_out = crops + (size_t)M * HEIGHT * mw * 3;

    dim3 block((HEIGHT / 2) * mw);   // 256 threads for mw=64
    dim3 grid(M);
    roi_rotate_kernel<<<grid, block, 0, stream>>>(images, boxes, box_indices,
                                                  crops, width_out, mw, Himg, Wimg);
}

// Round 4
// 37.123 us; speedup vs baseline: 1.5118x; 1.5118x over previous
//
#include <hip/hip_runtime.h>

#define HEIGHT 8

// One block per box, 512 threads: wave = one output row (i = tid/64),
// lane = column j. Per valid sample: TWO 24-byte row-segment loads
// (dwordx4 + dwordx2 each) covering both x-pixels x 3 channels, replacing
// 12 scalar dword gathers. Border clamp folded into fx/fy via the
// "clamped => fractional weight is 0" identity, so all register indexing
// is compile-time constant (no scratch).
__global__ void __launch_bounds__(512)
roi_rotate_kernel(const float* __restrict__ images,
                  const float* __restrict__ boxes,
                  const int* __restrict__ box_indices,
                  float* __restrict__ crops,
                  float* __restrict__ width_out,
                  int max_width, int Himg, int Wimg)
{
    const int m   = blockIdx.x;
    const int tid = threadIdx.x;
    const int mw  = max_width;
    const int i   = tid / mw;          // row    (wave-uniform for mw=64)
    const int j   = tid - i * mw;      // column (= lane)

    // Block-uniform box params -> scalar loads, no LDS needed.
    const float x1  = boxes[m * 5 + 0];
    const float y1  = boxes[m * 5 + 1];
    const float x2  = boxes[m * 5 + 2];
    const float y2  = boxes[m * 5 + 3];
    const float ang = boxes[m * 5 + 4];
    const float bwd = x2 - x1, bhd = y2 - y1;
    const float width = (float)HEIGHT * bwd / bhd;
    const float cx = (x1 + x2) * 0.5f;
    const float cy = (y1 + y2) * 0.5f;
    const float s  = bhd / (float)HEIGHT;
    const float ca = cosf(ang);
    const float sa = sinf(ang);
    if (tid == 0) width_out[m] = (float)mw - width;

    const float dx = s * ((float)j - (width - 1.0f) * 0.5f);
    const float dy = s * ((float)i - ((float)HEIGHT - 1.0f) * 0.5f);
    const float sx = cx + ca * dx - sa * dy;
    const float sy = cy + sa * dx + ca * dy;

    float v0 = 0.0f, v1 = 0.0f, v2 = 0.0f;

    const bool valid = ((float)j < ceilf(width)) &&
                       (sx >= 0.0f) && (sx <= (float)(Wimg - 1)) &&
                       (sy >= 0.0f) && (sy <= (float)(Himg - 1));

    if (valid) {
        const float x0 = floorf(sx);   // in [0, W-1] given valid
        const float y0 = floorf(sy);   // in [0, H-1]
        const int x0i = (int)x0;
        const int y0i = (int)y0;

        // Segment bases clamped so both loaded pixels stay in-image.
        const int xb = min(x0i, Wimg - 2);
        const int yb = min(y0i, Himg - 2);
        // If clamped (only possible when the fractional part is exactly 0),
        // shift full weight onto the high element instead of indexing.
        const float fx = (x0i == xb) ? (sx - x0) : 1.0f;
        const float fy = (y0i == yb) ? (sy - y0) : 1.0f;

        const int b = box_indices[m];
        const float* img = images + (size_t)b * Himg * Wimg * 3;
        const float* r0 = img + ((size_t)yb * Wimg + xb) * 3;
        const float* r1 = r0 + (size_t)Wimg * 3;

        float s0[6], s1[6];
        __builtin_memcpy(s0, r0, 24);   // row yb  : x0(c0,c1,c2), x0+1(c0,c1,c2)
        __builtin_memcpy(s1, r1, 24);   // row yb+1: same layout

        const float w00 = (1.0f - fx) * (1.0f - fy);
        const float w01 = fx * (1.0f - fy);
        const float w10 = (1.0f - fx) * fy;
        const float w11 = fx * fy;

        v0 = s0[0] * w00 + s0[3] * w01 + s1[0] * w10 + s1[3] * w11;
        v1 = s0[1] * w00 + s0[4] * w01 + s1[1] * w10 + s1[4] * w11;
        v2 = s0[2] * w00 + s0[5] * w01 + s1[2] * w10 + s1[5] * w11;
    }

    // Direct store: 64 lanes x 12B contiguous per wave -> coalesced.
    float* o = crops + ((size_t)(m * HEIGHT + i) * mw + j) * 3;
    o[0] = v0; o[1] = v1; o[2] = v2;
}

extern "C" void kernel_launch(void* const* d_in, const int* in_sizes, int n_in,
                              void* d_out, int out_size, void* d_ws, size_t ws_size,
                              hipStream_t stream) {
    const float* images      = (const float*)d_in[0];
    const float* boxes       = (const float*)d_in[2];
    const int*   box_indices = (const int*)d_in[3];

    const int M  = in_sizes[3];                       // 8192 boxes
    const int mw = (out_size - M) / (M * HEIGHT * 3); // max_width (=64)
    const int Himg = 512, Wimg = 512;

    float* crops     = (float*)d_out;
    float* width_out = crops + (size_t)M * HEIGHT * mw * 3;

    dim3 block(HEIGHT * mw);   // 512 threads = one box
    dim3 grid(M);
    roi_rotate_kernel<<<grid, block, 0, stream>>>(images, boxes, box_indices,
                                                  crops, width_out, mw, Himg, Wimg);
}